// Round 3
// baseline (98.275 us; speedup 1.0000x reference)
//
#include <hip/hip_runtime.h>

#define BLOCK  256
#define SPT    8      // sources per thread
#define SPB    16     // sources per block (2 source-groups of SPT)
#define NSLICE 128    // target slices = threads per source-group
#define CH     1024   // targets staged in LDS per chunk (16 KB of float4)

// Single-kernel exact 1-NN loss:
//   loss = mean_b mean_n min_m ||s_bn - t_bm||^2 / 3
//        = sum over sources of (|s|^2 + min_m (|t|^2 - 2 s.t)) * scale
// Each block: 16 sources (one batch), scans all M targets via LDS chunks.
// Thread (sg, g): sources sg*8..sg*8+7, target slice g (stride-128).
// Each ds_read_b128 (one target float4) feeds 8 sources x 4 VALU = 32 insts.
__global__ __launch_bounds__(BLOCK) void chamfer_min_kernel(
    const float* __restrict__ src, const float* __restrict__ tgt,
    float* __restrict__ out, int N, int M, int total_src, float scale)
{
    __shared__ float4 tpts[CH];
    __shared__ float red[4][SPT];  // per-wave partial mins

    const int tid = threadIdx.x;
    const int g   = tid & (NSLICE - 1);  // target slice 0..127
    const int sg  = tid >> 7;            // source group 0..1

    const int sbase = blockIdx.x * SPB + sg * SPT;
    const int b = (sbase < total_src) ? (sbase / N) : 0;
    const float* sb = src + (size_t)b * N * 3;
    const float* tb = tgt + (size_t)b * M * 3;

    float nsx[SPT], nsy[SPT], nsz[SPT], s2[SPT], mind[SPT];
    int vmask = 0;
#pragma unroll
    for (int u = 0; u < SPT; ++u) {
        int gsi = sbase + u;
        int si  = gsi - b * N;
        bool ok = (gsi < total_src) && (si >= 0) && (si < N);
        if (ok) vmask |= (1 << u);
        float x = 0.f, y = 0.f, z = 0.f;
        if (ok) {
            x = sb[(size_t)si * 3 + 0];
            y = sb[(size_t)si * 3 + 1];
            z = sb[(size_t)si * 3 + 2];
        }
        nsx[u] = -2.f * x;
        nsy[u] = -2.f * y;
        nsz[u] = -2.f * z;
        s2[u]  = fmaf(x, x, fmaf(y, y, z * z));
        mind[u] = 1e30f;
    }

    for (int m0 = 0; m0 < M; m0 += CH) {
        // ---- stage chunk of targets as (x,y,z,|t|^2) ----
        for (int j = tid; j < CH; j += BLOCK) {
            int mi = m0 + j;
            float tx = 0.f, ty = 0.f, tz = 0.f, t2 = 1e30f;
            if (mi < M) {
                tx = tb[(size_t)mi * 3 + 0];
                ty = tb[(size_t)mi * 3 + 1];
                tz = tb[(size_t)mi * 3 + 2];
                t2 = fmaf(tx, tx, fmaf(ty, ty, tz * tz));
            }
            tpts[j] = make_float4(tx, ty, tz, t2);
        }
        __syncthreads();

        // ---- scan: 8 targets/thread/chunk, 8 independent min-chains ----
#pragma unroll
        for (int k = 0; k < CH / NSLICE; ++k) {
            float4 tp = tpts[k * NSLICE + g];
#pragma unroll
            for (int u = 0; u < SPT; ++u) {
                float d = fmaf(nsx[u], tp.x,
                          fmaf(nsy[u], tp.y,
                          fmaf(nsz[u], tp.z, tp.w)));
                mind[u] = fminf(mind[u], d);
            }
        }
        __syncthreads();
    }

    // ---- reduce min over the 128 slices of each source group ----
    // wave-level butterfly (each wave covers 64 slices of one sg)
#pragma unroll
    for (int u = 0; u < SPT; ++u) {
#pragma unroll
        for (int off = 1; off < 64; off <<= 1) {
            mind[u] = fminf(mind[u], __shfl_xor(mind[u], off, 64));
        }
    }

    const int lane = tid & 63;
    const int w    = tid >> 6;  // waves 0,1 -> sg0 ; waves 2,3 -> sg1
    if (lane == 0) {
#pragma unroll
        for (int u = 0; u < SPT; ++u) red[w][u] = mind[u];
    }
    __syncthreads();

    // tid 0 (sg0) and tid 128 (sg1) hold the right s2[]/vmask for their group
    if (lane == 0 && (w == 0 || w == 2)) {
        float ssum = 0.f;
#pragma unroll
        for (int u = 0; u < SPT; ++u) {
            float mv = fminf(red[w][u], red[w + 1][u]);
            if (vmask & (1 << u)) ssum += s2[u] + mv;
        }
        atomicAdd(out, ssum * scale);
    }
}

extern "C" void kernel_launch(void* const* d_in, const int* in_sizes, int n_in,
                              void* d_out, int out_size, void* d_ws, size_t ws_size,
                              hipStream_t stream) {
    const float* src = (const float*)d_in[0];  // [B, N, 3] fp32
    const float* tgt = (const float*)d_in[1];  // [B, M, 3] fp32
    float* out = (float*)d_out;                // scalar fp32

    const int B = 2;
    const int N = in_sizes[0] / (B * 3);
    const int M = in_sizes[1] / (B * 3);
    const int total_src = B * N;

    hipMemsetAsync(d_out, 0, sizeof(float), stream);

    const int grid = (total_src + SPB - 1) / SPB;  // 1024 blocks at B=2,N=8192
    chamfer_min_kernel<<<grid, BLOCK, 0, stream>>>(
        src, tgt, out, N, M, total_src, 1.0f / (3.0f * (float)N * (float)B));
}

// Round 4
// 89.902 us; speedup vs baseline: 1.0931x; 1.0931x over previous
//
#include <hip/hip_runtime.h>

#define BLOCK  256
#define SPT    16     // sources per thread (16 independent min-chains)
#define NGRP   2      // source groups per block
#define SPB    (SPT * NGRP)          // 32 sources per block
#define NSLICE 128    // target slices = threads per source-group
#define CH     2048   // targets per LDS chunk (32 KB of float4)
#define PF     (CH / BLOCK)          // 8 staged targets per thread per chunk

// Exact 1-NN loss, one kernel:
//   loss = sum_sources (|s|^2 + min_m (|t|^2 - 2 s.t)) / (3*N*B)
// Block owns 32 sources; threads slice targets 128-way. Double-buffered LDS
// staging: prefetch chunk k+1 into registers while computing chunk k from
// LDS, write to the alternate buffer, ONE barrier per chunk. Each
// ds_read_b128 feeds 16 sources x 4 VALU = 64 insts.
__global__ __launch_bounds__(BLOCK) void chamfer_min_kernel(
    const float* __restrict__ src, const float* __restrict__ tgt,
    float* __restrict__ out, int N, int M, int total_src, float scale)
{
    __shared__ float4 tpts[2][CH];     // 64 KB -> 2 blocks/CU
    __shared__ float red[2 * NGRP][SPT];

    const int tid = threadIdx.x;
    const int g   = tid & (NSLICE - 1);  // target slice
    const int sg  = tid >> 7;            // source group 0..1

    const int sbase = blockIdx.x * SPB + sg * SPT;
    const int b = (sbase < total_src) ? (sbase / N) : 0;
    const float* sb = src + (size_t)b * N * 3;
    const float* tb = tgt + (size_t)b * M * 3;

    // ---- private sources, pre-scaled by -2 ----
    float nsx[SPT], nsy[SPT], nsz[SPT], s2[SPT], mind[SPT];
    int vmask = 0;
#pragma unroll
    for (int u = 0; u < SPT; ++u) {
        int gsi = sbase + u;
        int si  = gsi - b * N;
        bool ok = (gsi < total_src) && (si >= 0) && (si < N);
        if (ok) vmask |= (1 << u);
        float x = 0.f, y = 0.f, z = 0.f;
        if (ok) {
            x = sb[(size_t)si * 3 + 0];
            y = sb[(size_t)si * 3 + 1];
            z = sb[(size_t)si * 3 + 2];
        }
        nsx[u] = -2.f * x;  nsy[u] = -2.f * y;  nsz[u] = -2.f * z;
        s2[u]  = fmaf(x, x, fmaf(y, y, z * z));
        mind[u] = 1e30f;
    }

    const int nch = (M + CH - 1) / CH;

    // ---- stage chunk 0 ----
    float px[PF], py[PF], pz[PF];
#pragma unroll
    for (int j = 0; j < PF; ++j) {
        int mi = tid + j * BLOCK;
        bool ok = mi < M;
        px[j] = ok ? tb[(size_t)mi * 3 + 0] : 0.f;
        py[j] = ok ? tb[(size_t)mi * 3 + 1] : 0.f;
        pz[j] = ok ? tb[(size_t)mi * 3 + 2] : 0.f;
        float t2 = ok ? fmaf(px[j], px[j], fmaf(py[j], py[j], pz[j] * pz[j]))
                      : 1e30f;
        tpts[0][mi - 0] = make_float4(px[j], py[j], pz[j], t2);
    }
    __syncthreads();

    for (int c = 0; c < nch; ++c) {
        const int cur = c & 1;

        // ---- prefetch chunk c+1 into registers (hidden under compute) ----
        const bool more = (c + 1) < nch;
        if (more) {
            int m0n = (c + 1) * CH;
#pragma unroll
            for (int j = 0; j < PF; ++j) {
                int mi = m0n + tid + j * BLOCK;
                bool ok = mi < M;
                px[j] = ok ? tb[(size_t)mi * 3 + 0] : 0.f;
                py[j] = ok ? tb[(size_t)mi * 3 + 1] : 0.f;
                pz[j] = ok ? tb[(size_t)mi * 3 + 2] : 0.f;
            }
        }

        // ---- compute chunk c: 16 targets/thread, 16 sources each ----
#pragma unroll
        for (int k = 0; k < CH / NSLICE; ++k) {
            float4 tp = tpts[cur][k * NSLICE + g];
#pragma unroll
            for (int u = 0; u < SPT; ++u) {
                float d = fmaf(nsx[u], tp.x,
                          fmaf(nsy[u], tp.y,
                          fmaf(nsz[u], tp.z, tp.w)));
                mind[u] = fminf(mind[u], d);
            }
        }

        // ---- write prefetched chunk to the alternate buffer ----
        if (more) {
            int m0n = (c + 1) * CH;
#pragma unroll
            for (int j = 0; j < PF; ++j) {
                int mi = m0n + tid + j * BLOCK;
                float t2 = (mi < M)
                    ? fmaf(px[j], px[j], fmaf(py[j], py[j], pz[j] * pz[j]))
                    : 1e30f;
                tpts[cur ^ 1][tid + j * BLOCK] = make_float4(px[j], py[j], pz[j], t2);
            }
        }
        __syncthreads();
    }

    // ---- min over the 128 slices of each source group ----
#pragma unroll
    for (int u = 0; u < SPT; ++u) {
#pragma unroll
        for (int off = 1; off < 64; off <<= 1) {
            mind[u] = fminf(mind[u], __shfl_xor(mind[u], off, 64));
        }
    }

    const int lane = tid & 63;
    const int w    = tid >> 6;  // waves 0,1 -> sg0 ; waves 2,3 -> sg1
    if (lane == 0) {
#pragma unroll
        for (int u = 0; u < SPT; ++u) red[w][u] = mind[u];
    }
    __syncthreads();

    if (lane == 0 && ((w & 1) == 0)) {
        float ssum = 0.f;
#pragma unroll
        for (int u = 0; u < SPT; ++u) {
            float mv = fminf(red[w][u], red[w + 1][u]);
            if (vmask & (1 << u)) ssum += s2[u] + mv;
        }
        atomicAdd(out, ssum * scale);
    }
}

extern "C" void kernel_launch(void* const* d_in, const int* in_sizes, int n_in,
                              void* d_out, int out_size, void* d_ws, size_t ws_size,
                              hipStream_t stream) {
    const float* src = (const float*)d_in[0];  // [B, N, 3] fp32
    const float* tgt = (const float*)d_in[1];  // [B, M, 3] fp32
    float* out = (float*)d_out;                // scalar fp32

    const int B = 2;
    const int N = in_sizes[0] / (B * 3);
    const int M = in_sizes[1] / (B * 3);
    const int total_src = B * N;

    hipMemsetAsync(d_out, 0, sizeof(float), stream);

    const int grid = (total_src + SPB - 1) / SPB;  // 512 blocks at B=2,N=8192
    chamfer_min_kernel<<<grid, BLOCK, 0, stream>>>(
        src, tgt, out, N, M, total_src, 1.0f / (3.0f * (float)N * (float)B));
}

// Round 5
// 83.904 us; speedup vs baseline: 1.1713x; 1.0715x over previous
//
#include <hip/hip_runtime.h>

#define BLOCK  256
#define SPT    16     // sources per block (uniform across block -> SGPRs)
#define NSLICE 256    // target slices = threads per block

// ---- Kernel A: repack targets once into (x,y,z,|t|^2) float4 in d_ws ----
__global__ __launch_bounds__(256) void prep_kernel(
    const float* __restrict__ tgt, float4* __restrict__ tpre,
    int M, int Mp, int total)
{
    int i = blockIdx.x * 256 + threadIdx.x;
    if (i >= total) return;
    int b = i / Mp, m = i - b * Mp;
    float x = 0.f, y = 0.f, z = 0.f, t2 = 1e30f;  // sentinel: never wins min
    if (m < M) {
        const float* p = tgt + ((size_t)b * M + m) * 3;
        x = p[0]; y = p[1]; z = p[2];
        t2 = fmaf(x, x, fmaf(y, y, z * z));
    }
    tpre[i] = make_float4(x, y, z, t2);
}

// ---- Kernel B: exact 1-NN loss, no LDS staging, no hot-loop barriers ----
// Block owns SPT sources (same for all threads -> scalar loads / SGPRs).
// Thread tid scans targets tid, tid+256, ... : coalesced global_load_dwordx4
// straight from L2-resident repacked array. 2 targets/iter -> v_min3 folding.
__global__ __launch_bounds__(BLOCK) void chamfer_min_kernel(
    const float* __restrict__ src, const float4* __restrict__ tpre,
    float* __restrict__ out, int N, int Mp, int total_src, float scale)
{
    const int tid = threadIdx.x;
    const int sbase = blockIdx.x * SPT;
    const int b = (sbase < total_src) ? (sbase / N) : 0;
    const float* sb = src + (size_t)b * N * 3;
    const float4* tb = tpre + (size_t)b * Mp;

    // block-uniform source data (compiler scalarizes these loads)
    float nsx[SPT], nsy[SPT], nsz[SPT], s2[SPT], mind[SPT];
    unsigned vmask = 0;
#pragma unroll
    for (int u = 0; u < SPT; ++u) {
        int gsi = sbase + u;
        int si  = gsi - b * N;
        bool ok = (gsi < total_src) && (si >= 0) && (si < N);
        if (ok) vmask |= (1u << u);
        float x = 0.f, y = 0.f, z = 0.f;
        if (ok) {
            x = sb[(size_t)si * 3 + 0];
            y = sb[(size_t)si * 3 + 1];
            z = sb[(size_t)si * 3 + 2];
        }
        nsx[u] = -2.f * x;  nsy[u] = -2.f * y;  nsz[u] = -2.f * z;
        s2[u]  = fmaf(x, x, fmaf(y, y, z * z));
        mind[u] = 1e30f;
    }

    // hot loop: 2 coalesced float4 loads + 7 VALU per 2 pairs per source
    const int iters = Mp / NSLICE;  // Mp is a multiple of 2*NSLICE
#pragma unroll 4
    for (int k = 0; k < iters; k += 2) {
        float4 t0 = tb[(size_t)k * NSLICE + tid];
        float4 t1 = tb[(size_t)(k + 1) * NSLICE + tid];
#pragma unroll
        for (int u = 0; u < SPT; ++u) {
            float d0 = fmaf(nsx[u], t0.x,
                       fmaf(nsy[u], t0.y, fmaf(nsz[u], t0.z, t0.w)));
            float d1 = fmaf(nsx[u], t1.x,
                       fmaf(nsy[u], t1.y, fmaf(nsz[u], t1.z, t1.w)));
            mind[u] = fminf(mind[u], fminf(d0, d1));  // -> v_min3_f32
        }
    }

    // reduce: 64-lane butterfly per source, then across the 4 waves via LDS
#pragma unroll
    for (int u = 0; u < SPT; ++u) {
#pragma unroll
        for (int off = 1; off < 64; off <<= 1) {
            mind[u] = fminf(mind[u], __shfl_xor(mind[u], off, 64));
        }
    }

    __shared__ float red[BLOCK / 64][SPT];
    const int lane = tid & 63;
    const int w    = tid >> 6;
    if (lane == 0) {
#pragma unroll
        for (int u = 0; u < SPT; ++u) red[w][u] = mind[u];
    }
    __syncthreads();

    if (tid == 0) {
        float ssum = 0.f;
#pragma unroll
        for (int u = 0; u < SPT; ++u) {
            float mv = red[0][u];
#pragma unroll
            for (int ww = 1; ww < BLOCK / 64; ++ww) mv = fminf(mv, red[ww][u]);
            if (vmask & (1u << u)) ssum += s2[u] + mv;
        }
        atomicAdd(out, ssum * scale);
    }
}

extern "C" void kernel_launch(void* const* d_in, const int* in_sizes, int n_in,
                              void* d_out, int out_size, void* d_ws, size_t ws_size,
                              hipStream_t stream) {
    const float* src = (const float*)d_in[0];  // [B, N, 3] fp32
    const float* tgt = (const float*)d_in[1];  // [B, M, 3] fp32
    float* out = (float*)d_out;                // scalar fp32

    const int B = 2;
    const int N = in_sizes[0] / (B * 3);
    const int M = in_sizes[1] / (B * 3);
    const int total_src = B * N;

    // padded targets-per-batch: multiple of 2*NSLICE so the hot loop is exact
    const int Mp = ((M + 2 * NSLICE - 1) / (2 * NSLICE)) * (2 * NSLICE);
    float4* tpre = (float4*)d_ws;  // B*Mp*16 bytes (256 KB) << ws_size

    hipMemsetAsync(d_out, 0, sizeof(float), stream);

    const int prep_total = B * Mp;
    prep_kernel<<<(prep_total + 255) / 256, 256, 0, stream>>>(
        tgt, tpre, M, Mp, prep_total);

    const int grid = (total_src + SPT - 1) / SPT;  // 1024 blocks
    chamfer_min_kernel<<<grid, BLOCK, 0, stream>>>(
        src, tpre, out, N, Mp, total_src,
        1.0f / (3.0f * (float)N * (float)B));
}

// Round 6
// 77.298 us; speedup vs baseline: 1.2714x; 1.0855x over previous
//
#include <hip/hip_runtime.h>

#define BLOCK  256
#define SPT    16     // sources per block (block-uniform -> SGPRs)
#define NSLICE 256    // target slices = threads per block
#define UN     8      // targets per unrolled chunk (8 loads in flight)

typedef float vfloat2 __attribute__((ext_vector_type(2)));

// ---- Kernel A: repack targets once into (x,y,z,|t|^2); also zero d_out ----
__global__ __launch_bounds__(256) void prep_kernel(
    const float* __restrict__ tgt, float4* __restrict__ tpre,
    float* __restrict__ out, int M, int Mp, int total)
{
    int i = blockIdx.x * 256 + threadIdx.x;
    if (i == 0) out[0] = 0.f;  // replaces a separate hipMemsetAsync node
    if (i >= total) return;
    int b = i / Mp, m = i - b * Mp;
    float x = 0.f, y = 0.f, z = 0.f, t2 = 1e30f;  // pad sentinel: never wins
    if (m < M) {
        const float* p = tgt + ((size_t)b * M + m) * 3;
        x = p[0]; y = p[1]; z = p[2];
        t2 = fmaf(x, x, fmaf(y, y, z * z));
    }
    tpre[i] = make_float4(x, y, z, t2);
}

// ---- Kernel B: exact 1-NN loss via packed-f32 pairs ----
// Block owns SPT uniform sources; thread tid scans targets tid+256k
// (coalesced dwordx4 from the L2-resident repacked array). Two targets per
// step: 3 v_pk_fma_f32 + 1 v_min3_f32 per source = 2 VALU insts per pair.
__global__ __launch_bounds__(BLOCK) void chamfer_min_kernel(
    const float* __restrict__ src, const float4* __restrict__ tpre,
    float* __restrict__ out, int N, int Mp, int total_src, float scale)
{
    const int tid = threadIdx.x;
    const int sbase = blockIdx.x * SPT;
    const int b = (sbase < total_src) ? (sbase / N) : 0;
    const float* sb = src + (size_t)b * N * 3;
    const float4* tb = tpre + (size_t)b * Mp;

    // block-uniform sources, pre-scaled by -2 (SGPR-resident splats)
    vfloat2 nsx2[SPT], nsy2[SPT], nsz2[SPT];
    float s2[SPT], mind[SPT];
    unsigned vmask = 0;
#pragma unroll
    for (int u = 0; u < SPT; ++u) {
        int gsi = sbase + u;
        int si  = gsi - b * N;
        bool ok = (gsi < total_src) && (si >= 0) && (si < N);
        if (ok) vmask |= (1u << u);
        float x = 0.f, y = 0.f, z = 0.f;
        if (ok) {
            x = sb[(size_t)si * 3 + 0];
            y = sb[(size_t)si * 3 + 1];
            z = sb[(size_t)si * 3 + 2];
        }
        nsx2[u] = (vfloat2){-2.f * x, -2.f * x};
        nsy2[u] = (vfloat2){-2.f * y, -2.f * y};
        nsz2[u] = (vfloat2){-2.f * z, -2.f * z};
        s2[u]   = fmaf(x, x, fmaf(y, y, z * z));
        mind[u] = 1e30f;
    }

    const int TPT = Mp / NSLICE;  // targets per thread (Mp multiple of NSLICE*UN)
    for (int k0 = 0; k0 < TPT; k0 += UN) {
        float4 t[UN];
#pragma unroll
        for (int j = 0; j < UN; ++j) {
            t[j] = tb[(size_t)(k0 + j) * NSLICE + tid];
        }
#pragma unroll
        for (int j = 0; j < UN; j += 2) {
            vfloat2 cx = {t[j].x, t[j + 1].x};
            vfloat2 cy = {t[j].y, t[j + 1].y};
            vfloat2 cz = {t[j].z, t[j + 1].z};
            vfloat2 cw = {t[j].w, t[j + 1].w};
#pragma unroll
            for (int u = 0; u < SPT; ++u) {
                vfloat2 d = __builtin_elementwise_fma(nsx2[u], cx,
                            __builtin_elementwise_fma(nsy2[u], cy,
                            __builtin_elementwise_fma(nsz2[u], cz, cw)));
                mind[u] = fminf(mind[u], fminf(d.x, d.y));  // -> v_min3_f32
            }
        }
    }

    // reduce: 64-lane butterfly per source, then across 4 waves via LDS
#pragma unroll
    for (int u = 0; u < SPT; ++u) {
#pragma unroll
        for (int off = 1; off < 64; off <<= 1) {
            mind[u] = fminf(mind[u], __shfl_xor(mind[u], off, 64));
        }
    }

    __shared__ float red[BLOCK / 64][SPT];
    const int lane = tid & 63;
    const int w    = tid >> 6;
    if (lane == 0) {
#pragma unroll
        for (int u = 0; u < SPT; ++u) red[w][u] = mind[u];
    }
    __syncthreads();

    if (tid == 0) {
        float ssum = 0.f;
#pragma unroll
        for (int u = 0; u < SPT; ++u) {
            float mv = red[0][u];
#pragma unroll
            for (int ww = 1; ww < BLOCK / 64; ++ww) mv = fminf(mv, red[ww][u]);
            if (vmask & (1u << u)) ssum += s2[u] + mv;
        }
        atomicAdd(out, ssum * scale);
    }
}

extern "C" void kernel_launch(void* const* d_in, const int* in_sizes, int n_in,
                              void* d_out, int out_size, void* d_ws, size_t ws_size,
                              hipStream_t stream) {
    const float* src = (const float*)d_in[0];  // [B, N, 3] fp32
    const float* tgt = (const float*)d_in[1];  // [B, M, 3] fp32
    float* out = (float*)d_out;                // scalar fp32

    const int B = 2;
    const int N = in_sizes[0] / (B * 3);
    const int M = in_sizes[1] / (B * 3);
    const int total_src = B * N;

    // pad targets-per-batch to a multiple of NSLICE*UN for an exact hot loop
    const int step = NSLICE * UN;
    const int Mp = ((M + step - 1) / step) * step;
    float4* tpre = (float4*)d_ws;  // B*Mp*16 bytes << ws_size

    const int prep_total = B * Mp;
    prep_kernel<<<(prep_total + 255) / 256, 256, 0, stream>>>(
        tgt, tpre, out, M, Mp, prep_total);

    const int grid = (total_src + SPT - 1) / SPT;  // 1024 blocks
    chamfer_min_kernel<<<grid, BLOCK, 0, stream>>>(
        src, tpre, out, N, Mp, total_src,
        1.0f / (3.0f * (float)N * (float)B));
}